// Round 1
// 274.472 us; speedup vs baseline: 1.0054x; 1.0054x over previous
//
#include <hip/hip_runtime.h>

// PolynomialKernel: per row of 128 fp32 values:
//   x_norm = x / max(||x||_2, 1e-12)
//   out[0:128]    = x_norm
//   out[128:8384] = triu(i<=j) products x_norm[i]*x_norm[j] * degree_scales[1]
// Rows = B*L = 8192. Output row stride 8384 fp32.
//
// v2: 4 rows/block (decode amortized 4x) + transposed LDS layout
// perm(m)=(m&3)*32+(m>>2) so lane-stride-4-element gathers are bank-conflict
// free + prescaled s_xi = xn*scales[1] (branchless inner loop).

#define DD 128
#define ROW_OUT (DD + DD * (DD + 1) / 2) /* 8384 */
#define NCHUNK (ROW_OUT / 4)             /* 2096 */
#define RPB 4                            /* rows per block */

__global__ __launch_bounds__(256) void poly_kernel(
    const float* __restrict__ x, const float* __restrict__ scales,
    float* __restrict__ out) {
  __shared__ __attribute__((aligned(16))) float s_plain[RPB][DD];  // xn
  __shared__ float s_xi[RPB][DD];  // xn * scales[1]
  __shared__ float s_xt[RPB][DD];  // xn, transposed: word (m&3)*32+(m>>2)

  const int tid = threadIdx.x;
  const int w = tid >> 6;  // wave id == row within block
  const int l = tid & 63;
  const int row0 = blockIdx.x * RPB;
  const float s2 = scales[1];

  // Stage: wave w normalizes row (row0+w). Coalesced float2 load (8 B/lane).
  {
    const float2 v = ((const float2*)(x + (size_t)(row0 + w) * DD))[l];
    float p = v.x * v.x + v.y * v.y;
#pragma unroll
    for (int off = 32; off >= 1; off >>= 1) p += __shfl_xor(p, off, 64);
    const float inv = 1.0f / fmaxf(sqrtf(p), 1e-12f);
    const float a = v.x * inv, b = v.y * inv;
    const int m0 = 2 * l, m1 = 2 * l + 1;
    s_plain[w][m0] = a;
    s_plain[w][m1] = b;
    s_xi[w][m0] = a * s2;
    s_xi[w][m1] = b * s2;
    s_xt[w][((m0 & 3) << 5) + (m0 >> 2)] = a;
    s_xt[w][((m1 & 3) << 5) + (m1 >> 2)] = b;
  }
  __syncthreads();

  float* __restrict__ o0 = out + (size_t)row0 * ROW_OUT;

  for (int p4 = tid; p4 < NCHUNK; p4 += 256) {
    const int p = p4 * 4;
    if (p < DD) {
      // degree-1 part: straight copy of xn (first 32 chunks only)
#pragma unroll
      for (int r = 0; r < RPB; ++r)
        ((float4*)(o0 + (size_t)r * ROW_OUT))[p4] =
            ((const float4*)s_plain[r])[p4];
    } else {
      // ---- decode chunk -> per-element (i, j), shared by all 4 rows ----
      const int k = p - DD;  // 0 .. 8255, 4-aligned
      // i = floor((257 - sqrt(257^2 - 8k)) / 2); radicand is a perfect
      // square (257-2i)^2 at row starts -> float sqrt exact there.
      const float rr = sqrtf((float)(257 * 257 - 8 * k));
      int i = (int)((257.0f - rr) * 0.5f);
      int off = (i * (257 - i)) >> 1;
      if (off > k) {
        --i;
        off = (i * (257 - i)) >> 1;
      } else {
        const int off2 = ((i + 1) * (256 - i)) >> 1;
        if (off2 <= k) {
          ++i;
          off = off2;
        }
      }
      int j = i + (k - off);
      int ixi[4], ixt[4];
#pragma unroll
      for (int e = 0; e < 4; ++e) {
        if (j >= DD) {  // wrap to next triangle row (cndmask, no branch)
          ++i;
          j = i;
        }
        ixi[e] = i;
        ixt[e] = ((j & 3) << 5) + (j >> 2);  // transposed word index
        ++j;
      }
      // ---- apply to 4 rows: 2 conflict-free LDS reads + 1 mul / element --
#pragma unroll
      for (int r = 0; r < RPB; ++r) {
        float4 v;
        v.x = s_xi[r][ixi[0]] * s_xt[r][ixt[0]];
        v.y = s_xi[r][ixi[1]] * s_xt[r][ixt[1]];
        v.z = s_xi[r][ixi[2]] * s_xt[r][ixt[2]];
        v.w = s_xi[r][ixi[3]] * s_xt[r][ixt[3]];
        ((float4*)(o0 + (size_t)r * ROW_OUT))[p4] = v;
      }
    }
  }
}

extern "C" void kernel_launch(void* const* d_in, const int* in_sizes, int n_in,
                              void* d_out, int out_size, void* d_ws,
                              size_t ws_size, hipStream_t stream) {
  const float* x = (const float*)d_in[0];
  const float* scales = (const float*)d_in[1];
  float* out = (float*)d_out;
  const int n_rows = in_sizes[0] / DD;  // 8192
  poly_kernel<<<n_rows / RPB, 256, 0, stream>>>(x, scales, out);
}